// Round 3
// baseline (277.869 us; speedup 1.0000x reference)
//
#include <hip/hip_runtime.h>
#include <hip/hip_bf16.h>

// B=16, T=512, E=256, A=8. Inputs f32 (+int32 mask), outputs f32:
//   d_out: [ output 16*512*256 | attn 128*512*512 ]
// R13: R12 + (a) PV batched over attr PAIRS: both P matrices of a pair live
// in LDS (2x16KB aliasing dead S region), each sentFB fragment loaded ONCE
// per pair -> sentFB L2 traffic halved (1GB -> 512MB; L2 stream was the
// post-swizzle bottleneck: 1.3GB @ 34.5TB/s ~ 38us ~ kernel time);
// (b) k_out reverted to proven R10 256-thread shape (+unroll4) -- the R11
// 512-thread rework was never isolated and is the suspected parity-eater.
// Keeps: XCD-chunked swizzle (R12), z=2 a-split, lgkm-only barriers (R11).

#define Bt 16
#define Tt 512
#define Et 256
#define At 8

typedef __attribute__((ext_vector_type(8))) short short8;   // 8 x bf16
typedef __attribute__((ext_vector_type(4))) float floatx4;

static __device__ __forceinline__ unsigned short f2bf(float x) {
    union { float f; unsigned u; } v; v.f = x;
    unsigned r = v.u + 0x7fffu + ((v.u >> 16) & 1u);  // RNE
    return (unsigned short)(r >> 16);
}

static __device__ __forceinline__ floatx4 mfma16(short8 a, short8 b, floatx4 c) {
    return __builtin_amdgcn_mfma_f32_16x16x32_bf16(a, b, c, 0, 0, 0);
}

// Barrier that waits only on LDS ops (lgkmcnt), NOT on in-flight global
// stores (vmcnt). All barriers in k_attnpv protect LDS-only data
// (S / Pb / Xb / msk), so lgkm-only is sufficient (audited R11/R13).
static __device__ __forceinline__ void barrier_lds() {
    __builtin_amdgcn_sched_barrier(0);
    asm volatile("s_waitcnt lgkmcnt(0)" ::: "memory");
    __builtin_amdgcn_s_barrier();
    __builtin_amdgcn_sched_barrier(0);
}

// ---- prep: sentG (Gram frags, k=e) + sentFB (PV B-frags, k=s) ------------
// sentG block (bb, st in [0,32), ec in [0,8)): 512 shorts lane-major;
//   elem(l16,quad,j) = sent[bb][st*16+l16][ec*32+quad*8+j]
// sentFB block (bb, et in [0,16), sc in [0,16)):
//   elem(l16,quad,j) = sent[bb][sc*32+quad*8+j][et*16+l16]
__global__ __launch_bounds__(256) void k_prep_sent(const float* __restrict__ sent,
                                                   unsigned short* __restrict__ sentG,
                                                   unsigned short* __restrict__ sentFB) {
    int bb = blockIdx.z;
    int s0 = blockIdx.x * 32;       // 16
    int e0 = blockIdx.y * 32;       // 8
    __shared__ float tile[32][33];
    int c  = threadIdx.x & 31;
    int r4 = threadIdx.x >> 5;
    for (int i = 0; i < 4; ++i) {
        int r = r4 + 8 * i;
        tile[r][c] = sent[(bb * Tt + s0 + r) * Et + e0 + c];
    }
    __syncthreads();
    int wv = threadIdx.x >> 6, lane = threadIdx.x & 63, quad = lane >> 4, l16 = lane & 15;
    union { short8 s; unsigned short e[8]; } u;
    if (wv < 2) {
        // sentG block (bb, st = s0/16 + wv, ec = e0/32)
#pragma unroll
        for (int j = 0; j < 8; ++j) u.e[j] = f2bf(tile[wv * 16 + l16][quad * 8 + j]);
        *(short8*)(sentG + (((size_t)(bb * 32 + (s0 >> 4) + wv)) * 8 + (e0 >> 5)) * 512
                   + lane * 8) = u.s;
    } else {
        int h = wv - 2;
        // sentFB block (bb, et = e0/16 + h, sc = s0/32)
#pragma unroll
        for (int j = 0; j < 8; ++j) u.e[j] = f2bf(tile[quad * 8 + j][h * 16 + l16]);
        *(short8*)(sentFB + (((size_t)(bb * 16 + (e0 >> 4) + h)) * 16 + (s0 >> 5)) * 512
                   + lane * 8) = u.s;
    }
}

// ---- prep: Wp (B-frag-major W), verified R9. Split over 8 y-blocks. ------
__global__ __launch_bounds__(256) void k_prep_w(const float* __restrict__ W,
                                                unsigned short* __restrict__ Wp) {
    int nt = blockIdx.x;                  // 16
    int pc = blockIdx.y;                  // 8 chunks of 2 p-iterations
    int wave = threadIdx.x >> 6, lane = threadIdx.x & 63, quad = lane >> 4, l16 = lane & 15;
    const int KK = At * Et;               // 2048
    for (int p = pc * 2; p < pc * 2 + 2; ++p) {
        int kc = wave + 4 * p;            // 64
        const float* src = W + (size_t)(nt * 16 + l16) * KK + kc * 32 + quad * 8;
        union { short8 s; unsigned short e[8]; } u;
#pragma unroll
        for (int j = 0; j < 8; ++j) u.e[j] = f2bf(src[j]);
        *(short8*)(Wp + (((size_t)nt * 64 + kc) << 9) + lane * 8) = u.s;
    }
}

// ---- fused: Gram + softmax + attn store + batched PV + X store -----------
// 1D grid, 1024 blocks, XCD-chunked swizzle (R12). Per block: 4 attrs in
// 2 pairs; each pair's two P matrices co-resident in LDS so every sentFB
// fragment read feeds TWO MFMAs.
__global__ __launch_bounds__(256) void k_attnpv(const unsigned short* __restrict__ sentG,
                                                const unsigned short* __restrict__ sentFB,
                                                const int* __restrict__ mask,
                                                const float* __restrict__ atr,
                                                float* __restrict__ attnf,
                                                unsigned short* __restrict__ Xws) {
    int hw = blockIdx.x;                        // 1024, 1024%8==0 -> bijective
    int logical = (hw & 7) * 128 + (hw >> 3);
    int z  = logical >> 9;                      // a-group 0/1
    int bb = (logical >> 5) & 15;               // 16
    int t0 = (logical & 31) * 16;               // 32 tiles
    int a0 = z * 4;
    __shared__ float S[16][516];    // 33 KB; a-loop reuses as Pb(2x16KB)/Xb(2x8KB)
    __shared__ float msk[512];
    __shared__ float mrowv[16];
    unsigned short* Pb = (unsigned short*)&S[0][0];   // pair: ai*8192 shorts
    unsigned short* Xb = (unsigned short*)&S[0][0];   // after PV: ai*4096 shorts

    int tid = threadIdx.x;
    for (int i = tid; i < 512; i += 256) msk[i] = (mask[bb * Tt + i] != 0) ? 1.0f : 0.0f;
    if (tid < 16) mrowv[tid] = (mask[bb * Tt + t0 + tid] != 0) ? 1.0f : 0.0f;
    barrier_lds();

    int wv = tid >> 6, lane = tid & 63, quad = lane >> 4, l16 = lane & 15;

    // ---- Gram: A and B frags both from frag-major sentG (contiguous 1KB/wave)
    const unsigned short* Gbase = sentG + ((size_t)(bb * 32 + (t0 >> 4)) * 8) * 512 + lane * 8;
    short8 af[8];
#pragma unroll
    for (int kk = 0; kk < 8; ++kk) af[kk] = *(const short8*)(Gbase + kk * 512);

#pragma unroll
    for (int i = 0; i < 8; ++i) {
        int nt = wv * 8 + i;
        const unsigned short* Bb = sentG + ((size_t)(bb * 32 + nt) * 8) * 512 + lane * 8;
        floatx4 c = {0.f, 0.f, 0.f, 0.f};
#pragma unroll
        for (int kk = 0; kk < 8; ++kk)
            c = mfma16(af[kk], *(const short8*)(Bb + kk * 512), c);
#pragma unroll
        for (int r = 0; r < 4; ++r) {
            int cidx = nt * 16 + l16;
            S[quad * 4 + r][cidx] = c[r] * msk[cidx] * mrowv[quad * 4 + r];
        }
    }
    barrier_lds();

    // ---- hoist masked scores to regs; one max-reduction for all attrs
    int row = tid >> 4, cl = tid & 15;
    float w[32];
    float wmax = -1e30f;
#pragma unroll
    for (int i4 = 0; i4 < 8; ++i4) {
        float4 v = *(const float4*)&S[row][i4 * 64 + cl * 4];
        w[i4 * 4 + 0] = v.x; w[i4 * 4 + 1] = v.y; w[i4 * 4 + 2] = v.z; w[i4 * 4 + 3] = v.w;
        wmax = fmaxf(wmax, fmaxf(fmaxf(v.x, v.y), fmaxf(v.z, v.w)));
    }
#pragma unroll
    for (int off = 8; off >= 1; off >>= 1) wmax = fmaxf(wmax, __shfl_xor(wmax, off, 64));
    barrier_lds();    // all S reads done before Pb overwrites the region

    for (int ph = 0; ph < 2; ++ph) {
        int ap = a0 + ph * 2;           // pair base attr

        // ---- softmax + attn store + Pb write, for both attrs of the pair
#pragma unroll
        for (int ai = 0; ai < 2; ++ai) {
            int a = ap + ai;
            float av = atr[bb * At + a];
            float coef = av * av * (1.0f / 16.0f);
            float mx = coef * wmax;
            float p[32];
            float sum = 0.f;
#pragma unroll
            for (int j = 0; j < 32; ++j) {
                float e = __expf(fmaf(coef, w[j], -mx));
                p[j] = e;
                sum += e;
            }
#pragma unroll
            for (int off = 8; off >= 1; off >>= 1) sum += __shfl_xor(sum, off, 64);
            float inv = 1.0f / sum;
#pragma unroll
            for (int j = 0; j < 32; ++j) p[j] *= inv;

            // attn f32 store (coalesced) -- fire-and-forget; lgkm-only
            // barriers below do NOT drain these.
            float* orow = attnf + ((size_t)(bb * At + a) * Tt + (t0 + row)) * Tt;
#pragma unroll
            for (int i4 = 0; i4 < 8; ++i4) {
                float4 v;
                v.x = p[i4 * 4 + 0]; v.y = p[i4 * 4 + 1];
                v.z = p[i4 * 4 + 2]; v.w = p[i4 * 4 + 3];
                *(float4*)(orow + i4 * 64 + cl * 4) = v;
            }

            // P -> LDS bf16 in chunk-XOR A-frag layout (cols i4*64+cl*4..+3)
#pragma unroll
            for (int i4 = 0; i4 < 8; ++i4) {
                unsigned b0 = __float_as_uint(p[i4 * 4 + 0]) + 0x8000u;
                unsigned b1 = __float_as_uint(p[i4 * 4 + 1]) + 0x8000u;
                unsigned b2 = __float_as_uint(p[i4 * 4 + 2]) + 0x8000u;
                unsigned b3 = __float_as_uint(p[i4 * 4 + 3]) + 0x8000u;
                uint2 pk;
                pk.x = __builtin_amdgcn_perm(b1, b0, 0x07060302u);
                pk.y = __builtin_amdgcn_perm(b3, b2, 0x07060302u);
                int h = i4 * 8 + (cl >> 1);
                *(uint2*)(Pb + ai * 8192 + row * 512 + ((h ^ (row & 7)) << 3)
                          + (cl & 1) * 4) = pk;
            }
        }
        barrier_lds();   // both Pb visible before PV reads (LDS only)

        // ---- PV batched over the pair: each bfr load feeds TWO MFMAs
        floatx4 pc0[4], pc1[4];
#pragma unroll
        for (int i = 0; i < 4; ++i) {
            pc0[i] = (floatx4){0.f, 0.f, 0.f, 0.f};
            pc1[i] = (floatx4){0.f, 0.f, 0.f, 0.f};
        }
        for (int kc = 0; kc < 16; ++kc) {
            int poff = l16 * 512 + (((kc * 4 + quad) ^ (l16 & 7)) << 3);
            short8 af0 = *(const short8*)(Pb + poff);
            short8 af1 = *(const short8*)(Pb + 8192 + poff);
#pragma unroll
            for (int i = 0; i < 4; ++i) {
                short8 bfr = *(const short8*)(sentFB +
                    (((size_t)(bb * 16 + wv * 4 + i) * 16 + kc) << 9) + lane * 8);
                pc0[i] = mfma16(af0, bfr, pc0[i]);
                pc1[i] = mfma16(af1, bfr, pc1[i]);
            }
        }
        barrier_lds();   // PV's Pb reads done before Xb overwrites region

        // ---- epilogue both attrs: X[b][t'][k], t' = a*64 + (t0>>3) + g
#pragma unroll
        for (int ai = 0; ai < 2; ++ai) {
            float av = atr[bb * At + ap + ai];
#pragma unroll
            for (int i = 0; i < 4; ++i) {
                int e = (wv * 4 + i) * 16 + l16;
#pragma unroll
                for (int r = 0; r < 4; ++r) {
                    int tl = quad * 4 + r;
                    float x = av * (ai ? pc1[i][r] : pc0[i][r]);
                    Xb[ai * 4096 + (tl >> 3) * 2048 + (tl & 7) * 256 + e] = f2bf(x);
                }
            }
        }
        barrier_lds();   // Xb visible before copy reads (LDS only)

        // ---- Xb -> Xws: 2x2 contiguous 4 KB rows (fire-and-forget stores)
#pragma unroll
        for (int ai = 0; ai < 2; ++ai) {
            int a = ap + ai;
            size_t xbase = ((size_t)bb * Tt + a * 64 + (t0 >> 3)) * 2048;
            int g = tid >> 7, off = (tid & 127) * 16;
            short8 v0 = *(const short8*)(Xb + ai * 4096 + g * 2048 + off);
            short8 v1 = *(const short8*)(Xb + ai * 4096 + g * 2048 + off + 8);
            *(short8*)(Xws + xbase + g * 2048 + off) = v0;
            *(short8*)(Xws + xbase + g * 2048 + off + 8) = v1;
        }
        barrier_lds();   // copy's LDS reads done before next pair's Pb writes
    }
}

// ---- K3: out = X @ W^T + bias (R10-proven 256-thread shape, +unroll4) ----
__global__ __launch_bounds__(256) void k_out(const unsigned short* __restrict__ Xws,
                                             const unsigned short* __restrict__ Wp,
                                             const float* __restrict__ bias,
                                             float* __restrict__ out) {
    int bb = blockIdx.y;            // 16
    int tp0 = blockIdx.x * 16;      // 32 tiles
    int tid = threadIdx.x;
    int wv = tid >> 6, lane = tid & 63, quad = lane >> 4, l16 = lane & 15;

    __shared__ unsigned short Xb[16 * 2048];    // 64 KB, XOR-chunk swizzled

    int rhat = tid >> 4;            // 0..15
    int hb   = tid & 15;
    const unsigned short* src = Xws + ((size_t)bb * Tt + tp0 + rhat) * 2048;
#pragma unroll
    for (int p = 0; p < 16; ++p) {
        int h = hb + 16 * p;
        short8 v = *(const short8*)(src + h * 8);
        *(short8*)(Xb + rhat * 2048 + ((h ^ (rhat & 7)) << 3)) = v;
    }
    __syncthreads();

    floatx4 oacc[4];
#pragma unroll
    for (int i = 0; i < 4; ++i) oacc[i] = (floatx4){0.f, 0.f, 0.f, 0.f};

    const int KK = At * Et;  // 2048
#pragma unroll 4
    for (int k0 = 0; k0 < KK; k0 += 32) {
        short8 afr = *(const short8*)(Xb + l16 * 2048 +
            ((((k0 >> 3) + quad) ^ (l16 & 7)) << 3));
#pragma unroll
        for (int i = 0; i < 4; ++i) {
            short8 bf = *(const short8*)(Wp +
                (((size_t)(wv * 4 + i) * 64 + (k0 >> 5)) << 9) + lane * 8);
            oacc[i] = mfma16(afr, bf, oacc[i]);
        }
    }
#pragma unroll
    for (int i = 0; i < 4; ++i) {
        int n = (wv * 4 + i) * 16 + l16;
        float bv = bias[n];
#pragma unroll
        for (int r = 0; r < 4; ++r) {
            int tp = tp0 + quad * 4 + r;
            out[((size_t)bb * Tt + tp) * Et + n] = oacc[i][r] + bv;
        }
    }
}

extern "C" void kernel_launch(void* const* d_in, const int* in_sizes, int n_in,
                              void* d_out, int out_size, void* d_ws, size_t ws_size,
                              hipStream_t stream) {
    const float* sent = (const float*)d_in[0];   // f32 (B,T,E)
    const int*   mask = (const int*)d_in[1];     // int32 (B,T)
    const float* atr  = (const float*)d_in[2];   // f32 (B,A)
    const float* W    = (const float*)d_in[3];   // f32 (E, A*E)
    const float* bias = (const float*)d_in[4];   // f32 (E)

    float* out0  = (float*)d_out;                     // 2,097,152 f32
    float* attnf = out0 + (size_t)Bt * Tt * Et;       // 33,554,432 f32

    char* ws = (char*)d_ws;
    unsigned short* sentG  = (unsigned short*)(ws);             // 4 MB
    unsigned short* sentFB = (unsigned short*)(ws + 4194304);   // 4 MB
    unsigned short* Wp     = (unsigned short*)(ws + 8388608);   // 1 MB
    unsigned short* Xws    = (unsigned short*)(ws + 9437184);   // 32 MB
    // total 42.99 MB (== R2/R9 proven-safe footprint)

    hipLaunchKernelGGL(k_prep_sent, dim3(Tt / 32, Et / 32, Bt), dim3(256), 0, stream,
                       sent, sentG, sentFB);
    hipLaunchKernelGGL(k_prep_w, dim3(16, 8), dim3(256), 0, stream, W, Wp);
    hipLaunchKernelGGL(k_attnpv, dim3(1024), dim3(256), 0, stream,
                       sentG, sentFB, mask, atr, attnf, Xws);
    hipLaunchKernelGGL(k_out, dim3(Tt / 16, Bt), dim3(256), 0, stream,
                       Xws, Wp, bias, out0);
}

// Round 4
// 235.329 us; speedup vs baseline: 1.1808x; 1.1808x over previous
//
#include <hip/hip_runtime.h>
#include <hip/hip_bf16.h>

// B=16, T=512, E=256, A=8. Inputs f32 (+int32 mask), outputs f32:
//   d_out: [ output 16*512*256 | attn 128*512*512 ]
// R14: R12 structure (single-attr PV, VGPR~116 -- R13's pair-PV reverted:
// it cost 144 VGPR / 11% occ / +46us) with a DEEPER a-split: z=4 groups x
// 2 attrs per block (2048 blocks, 8 blocks/CU of work vs 4). Attacks the
// measured symptom (all utils low, latency-bound serial chain): per-block
// chain halves, block generations pipeline. XCD swizzle re-derived bb-major:
// each XCD owns 2 bb slices (1MB sentG+sentFB working set in 4MB L2).
// Keeps: lgkm-only barriers (R11), k_prep_w 8-way split (R12),
// k_out = proven R10 256-thread shape + unroll4.

#define Bt 16
#define Tt 512
#define Et 256
#define At 8

typedef __attribute__((ext_vector_type(8))) short short8;   // 8 x bf16
typedef __attribute__((ext_vector_type(4))) float floatx4;

static __device__ __forceinline__ unsigned short f2bf(float x) {
    union { float f; unsigned u; } v; v.f = x;
    unsigned r = v.u + 0x7fffu + ((v.u >> 16) & 1u);  // RNE
    return (unsigned short)(r >> 16);
}

static __device__ __forceinline__ floatx4 mfma16(short8 a, short8 b, floatx4 c) {
    return __builtin_amdgcn_mfma_f32_16x16x32_bf16(a, b, c, 0, 0, 0);
}

// Barrier that waits only on LDS ops (lgkmcnt), NOT on in-flight global
// stores (vmcnt). All barriers in k_attnpv protect LDS-only data
// (S / Pb / Xb / msk), so lgkm-only is sufficient (audited R11/R12).
static __device__ __forceinline__ void barrier_lds() {
    __builtin_amdgcn_sched_barrier(0);
    asm volatile("s_waitcnt lgkmcnt(0)" ::: "memory");
    __builtin_amdgcn_s_barrier();
    __builtin_amdgcn_sched_barrier(0);
}

// ---- prep: sentG (Gram frags, k=e) + sentFB (PV B-frags, k=s) ------------
// sentG block (bb, st in [0,32), ec in [0,8)): 512 shorts lane-major;
//   elem(l16,quad,j) = sent[bb][st*16+l16][ec*32+quad*8+j]
// sentFB block (bb, et in [0,16), sc in [0,16)):
//   elem(l16,quad,j) = sent[bb][sc*32+quad*8+j][et*16+l16]
__global__ __launch_bounds__(256) void k_prep_sent(const float* __restrict__ sent,
                                                   unsigned short* __restrict__ sentG,
                                                   unsigned short* __restrict__ sentFB) {
    int bb = blockIdx.z;
    int s0 = blockIdx.x * 32;       // 16
    int e0 = blockIdx.y * 32;       // 8
    __shared__ float tile[32][33];
    int c  = threadIdx.x & 31;
    int r4 = threadIdx.x >> 5;
    for (int i = 0; i < 4; ++i) {
        int r = r4 + 8 * i;
        tile[r][c] = sent[(bb * Tt + s0 + r) * Et + e0 + c];
    }
    __syncthreads();
    int wv = threadIdx.x >> 6, lane = threadIdx.x & 63, quad = lane >> 4, l16 = lane & 15;
    union { short8 s; unsigned short e[8]; } u;
    if (wv < 2) {
        // sentG block (bb, st = s0/16 + wv, ec = e0/32)
#pragma unroll
        for (int j = 0; j < 8; ++j) u.e[j] = f2bf(tile[wv * 16 + l16][quad * 8 + j]);
        *(short8*)(sentG + (((size_t)(bb * 32 + (s0 >> 4) + wv)) * 8 + (e0 >> 5)) * 512
                   + lane * 8) = u.s;
    } else {
        int h = wv - 2;
        // sentFB block (bb, et = e0/16 + h, sc = s0/32)
#pragma unroll
        for (int j = 0; j < 8; ++j) u.e[j] = f2bf(tile[quad * 8 + j][h * 16 + l16]);
        *(short8*)(sentFB + (((size_t)(bb * 16 + (e0 >> 4) + h)) * 16 + (s0 >> 5)) * 512
                   + lane * 8) = u.s;
    }
}

// ---- prep: Wp (B-frag-major W), verified R9. Split over 8 y-blocks. ------
__global__ __launch_bounds__(256) void k_prep_w(const float* __restrict__ W,
                                                unsigned short* __restrict__ Wp) {
    int nt = blockIdx.x;                  // 16
    int pc = blockIdx.y;                  // 8 chunks of 2 p-iterations
    int wave = threadIdx.x >> 6, lane = threadIdx.x & 63, quad = lane >> 4, l16 = lane & 15;
    const int KK = At * Et;               // 2048
    for (int p = pc * 2; p < pc * 2 + 2; ++p) {
        int kc = wave + 4 * p;            // 64
        const float* src = W + (size_t)(nt * 16 + l16) * KK + kc * 32 + quad * 8;
        union { short8 s; unsigned short e[8]; } u;
#pragma unroll
        for (int j = 0; j < 8; ++j) u.e[j] = f2bf(src[j]);
        *(short8*)(Wp + (((size_t)nt * 64 + kc) << 9) + lane * 8) = u.s;
    }
}

// ---- fused: Gram + softmax + attn store + PV + X store -------------------
// 1D grid, 2048 blocks. bb-major XCD-chunked swizzle: XCD k runs logical
// [k*256,(k+1)*256) = bb in {2k,2k+1} x all z x all t0 -> 1MB sentG+sentFB
// working set per XCD L2. Per block: 2 attrs (z*2, z*2+1), R12 inner code.
__global__ __launch_bounds__(256) void k_attnpv(const unsigned short* __restrict__ sentG,
                                                const unsigned short* __restrict__ sentFB,
                                                const int* __restrict__ mask,
                                                const float* __restrict__ atr,
                                                float* __restrict__ attnf,
                                                unsigned short* __restrict__ Xws) {
    int hw = blockIdx.x;                        // 2048, 2048%8==0 -> bijective
    int logical = (hw & 7) * 256 + (hw >> 3);
    int bb = logical >> 7;                      // 16 (slow axis: 2 per XCD)
    int z  = (logical >> 5) & 3;                // a-group 0..3
    int t0 = (logical & 31) * 16;               // 32 tiles
    int a0 = z * 2;
    __shared__ float S[16][516];    // 33 KB; reused as Pb(16KB)+Xb(8KB) in a-loop
    __shared__ float msk[512];
    __shared__ float mrowv[16];
    unsigned short* Pb = (unsigned short*)&S[0][0];   // 16 rows x 512 bf16
    unsigned short* Xb = Pb + 8192;                    // 2 rows x 2048 bf16

    int tid = threadIdx.x;
    for (int i = tid; i < 512; i += 256) msk[i] = (mask[bb * Tt + i] != 0) ? 1.0f : 0.0f;
    if (tid < 16) mrowv[tid] = (mask[bb * Tt + t0 + tid] != 0) ? 1.0f : 0.0f;
    barrier_lds();

    int wv = tid >> 6, lane = tid & 63, quad = lane >> 4, l16 = lane & 15;

    // ---- Gram: A and B frags both from frag-major sentG (contiguous 1KB/wave)
    const unsigned short* Gbase = sentG + ((size_t)(bb * 32 + (t0 >> 4)) * 8) * 512 + lane * 8;
    short8 af[8];
#pragma unroll
    for (int kk = 0; kk < 8; ++kk) af[kk] = *(const short8*)(Gbase + kk * 512);

#pragma unroll
    for (int i = 0; i < 8; ++i) {
        int nt = wv * 8 + i;
        const unsigned short* Bb = sentG + ((size_t)(bb * 32 + nt) * 8) * 512 + lane * 8;
        floatx4 c = {0.f, 0.f, 0.f, 0.f};
#pragma unroll
        for (int kk = 0; kk < 8; ++kk)
            c = mfma16(af[kk], *(const short8*)(Bb + kk * 512), c);
#pragma unroll
        for (int r = 0; r < 4; ++r) {
            int cidx = nt * 16 + l16;
            S[quad * 4 + r][cidx] = c[r] * msk[cidx] * mrowv[quad * 4 + r];
        }
    }
    barrier_lds();

    // ---- hoist masked scores to regs; one max-reduction for all attrs
    int row = tid >> 4, cl = tid & 15;
    float w[32];
    float wmax = -1e30f;
#pragma unroll
    for (int i4 = 0; i4 < 8; ++i4) {
        float4 v = *(const float4*)&S[row][i4 * 64 + cl * 4];
        w[i4 * 4 + 0] = v.x; w[i4 * 4 + 1] = v.y; w[i4 * 4 + 2] = v.z; w[i4 * 4 + 3] = v.w;
        wmax = fmaxf(wmax, fmaxf(fmaxf(v.x, v.y), fmaxf(v.z, v.w)));
    }
#pragma unroll
    for (int off = 8; off >= 1; off >>= 1) wmax = fmaxf(wmax, __shfl_xor(wmax, off, 64));
    barrier_lds();    // all S reads done before Pb overwrites the region

    for (int a = a0; a < a0 + 2; ++a) {
        float av = atr[bb * At + a];
        float coef = av * av * (1.0f / 16.0f);
        float mx = coef * wmax;
        float p[32];
        float sum = 0.f;
#pragma unroll
        for (int j = 0; j < 32; ++j) {
            float e = __expf(fmaf(coef, w[j], -mx));
            p[j] = e;
            sum += e;
        }
#pragma unroll
        for (int off = 8; off >= 1; off >>= 1) sum += __shfl_xor(sum, off, 64);
        float inv = 1.0f / sum;
#pragma unroll
        for (int j = 0; j < 32; ++j) p[j] *= inv;

        // attn f32 store (coalesced) -- fire-and-forget; the lgkm-only
        // barriers below do NOT drain these.
        float* orow = attnf + ((size_t)(bb * At + a) * Tt + (t0 + row)) * Tt;
#pragma unroll
        for (int i4 = 0; i4 < 8; ++i4) {
            float4 v;
            v.x = p[i4 * 4 + 0]; v.y = p[i4 * 4 + 1];
            v.z = p[i4 * 4 + 2]; v.w = p[i4 * 4 + 3];
            *(float4*)(orow + i4 * 64 + cl * 4) = v;
        }

        // P -> LDS bf16 in chunk-XOR A-frag layout (cols i4*64+cl*4..+3)
#pragma unroll
        for (int i4 = 0; i4 < 8; ++i4) {
            unsigned b0 = __float_as_uint(p[i4 * 4 + 0]) + 0x8000u;
            unsigned b1 = __float_as_uint(p[i4 * 4 + 1]) + 0x8000u;
            unsigned b2 = __float_as_uint(p[i4 * 4 + 2]) + 0x8000u;
            unsigned b3 = __float_as_uint(p[i4 * 4 + 3]) + 0x8000u;
            uint2 pk;
            pk.x = __builtin_amdgcn_perm(b1, b0, 0x07060302u);
            pk.y = __builtin_amdgcn_perm(b3, b2, 0x07060302u);
            int h = i4 * 8 + (cl >> 1);
            *(uint2*)(Pb + row * 512 + ((h ^ (row & 7)) << 3) + (cl & 1) * 4) = pk;
        }
        barrier_lds();   // Pb writes visible before PV reads (LDS only)

        // PV: 16x256 = P(16x512) @ sf^T; wave wv owns e-tiles wv*4..+3
        floatx4 pacc[4];
#pragma unroll
        for (int i = 0; i < 4; ++i) pacc[i] = (floatx4){0.f, 0.f, 0.f, 0.f};
        for (int kc = 0; kc < 16; ++kc) {
            short8 afr = *(const short8*)(Pb + l16 * 512 +
                (((kc * 4 + quad) ^ (l16 & 7)) << 3));
#pragma unroll
            for (int i = 0; i < 4; ++i) {
                short8 bfr = *(const short8*)(sentFB +
                    (((size_t)(bb * 16 + wv * 4 + i) * 16 + kc) << 9) + lane * 8);
                pacc[i] = mfma16(afr, bfr, pacc[i]);
            }
        }

        // epilogue: X[b][t'][k], t' = a*64 + (t0>>3) + g, k = (tl&7)*256 + e
#pragma unroll
        for (int i = 0; i < 4; ++i) {
            int e = (wv * 4 + i) * 16 + l16;
#pragma unroll
            for (int r = 0; r < 4; ++r) {
                int tl = quad * 4 + r;
                Xb[(tl >> 3) * 2048 + (tl & 7) * 256 + e] = f2bf(av * pacc[i][r]);
            }
        }
        barrier_lds();   // Xb writes visible before copy reads (LDS only)

        // Xb -> Xws: 2 contiguous 4 KB rows (fire-and-forget global stores)
        {
            size_t xbase = ((size_t)bb * Tt + a * 64 + (t0 >> 3)) * 2048;
            int g = tid >> 7, off = (tid & 127) * 16;
            short8 v0 = *(const short8*)(Xb + g * 2048 + off);
            short8 v1 = *(const short8*)(Xb + g * 2048 + off + 8);
            *(short8*)(Xws + xbase + g * 2048 + off) = v0;
            *(short8*)(Xws + xbase + g * 2048 + off + 8) = v1;
        }
        // no sync needed at loop end: next a's Pb writes (region disjoint
        // from Xb) are ordered after that a's own barrier_lds, and each
        // wave's Xb LDS reads drain at its next lgkmcnt(0).
    }
}

// ---- K3: out = X @ W^T + bias (R10-proven 256-thread shape, +unroll4) ----
__global__ __launch_bounds__(256) void k_out(const unsigned short* __restrict__ Xws,
                                             const unsigned short* __restrict__ Wp,
                                             const float* __restrict__ bias,
                                             float* __restrict__ out) {
    int bb = blockIdx.y;            // 16
    int tp0 = blockIdx.x * 16;      // 32 tiles
    int tid = threadIdx.x;
    int wv = tid >> 6, lane = tid & 63, quad = lane >> 4, l16 = lane & 15;

    __shared__ unsigned short Xb[16 * 2048];    // 64 KB, XOR-chunk swizzled

    int rhat = tid >> 4;            // 0..15
    int hb   = tid & 15;
    const unsigned short* src = Xws + ((size_t)bb * Tt + tp0 + rhat) * 2048;
#pragma unroll
    for (int p = 0; p < 16; ++p) {
        int h = hb + 16 * p;
        short8 v = *(const short8*)(src + h * 8);
        *(short8*)(Xb + rhat * 2048 + ((h ^ (rhat & 7)) << 3)) = v;
    }
    __syncthreads();

    floatx4 oacc[4];
#pragma unroll
    for (int i = 0; i < 4; ++i) oacc[i] = (floatx4){0.f, 0.f, 0.f, 0.f};

    const int KK = At * Et;  // 2048
#pragma unroll 4
    for (int k0 = 0; k0 < KK; k0 += 32) {
        short8 afr = *(const short8*)(Xb + l16 * 2048 +
            ((((k0 >> 3) + quad) ^ (l16 & 7)) << 3));
#pragma unroll
        for (int i = 0; i < 4; ++i) {
            short8 bf = *(const short8*)(Wp +
                (((size_t)(wv * 4 + i) * 64 + (k0 >> 5)) << 9) + lane * 8);
            oacc[i] = mfma16(afr, bf, oacc[i]);
        }
    }
#pragma unroll
    for (int i = 0; i < 4; ++i) {
        int n = (wv * 4 + i) * 16 + l16;
        float bv = bias[n];
#pragma unroll
        for (int r = 0; r < 4; ++r) {
            int tp = tp0 + quad * 4 + r;
            out[((size_t)bb * Tt + tp) * Et + n] = oacc[i][r] + bv;
        }
    }
}

extern "C" void kernel_launch(void* const* d_in, const int* in_sizes, int n_in,
                              void* d_out, int out_size, void* d_ws, size_t ws_size,
                              hipStream_t stream) {
    const float* sent = (const float*)d_in[0];   // f32 (B,T,E)
    const int*   mask = (const int*)d_in[1];     // int32 (B,T)
    const float* atr  = (const float*)d_in[2];   // f32 (B,A)
    const float* W    = (const float*)d_in[3];   // f32 (E, A*E)
    const float* bias = (const float*)d_in[4];   // f32 (E)

    float* out0  = (float*)d_out;                     // 2,097,152 f32
    float* attnf = out0 + (size_t)Bt * Tt * Et;       // 33,554,432 f32

    char* ws = (char*)d_ws;
    unsigned short* sentG  = (unsigned short*)(ws);             // 4 MB
    unsigned short* sentFB = (unsigned short*)(ws + 4194304);   // 4 MB
    unsigned short* Wp     = (unsigned short*)(ws + 8388608);   // 1 MB
    unsigned short* Xws    = (unsigned short*)(ws + 9437184);   // 32 MB
    // total 42.99 MB (== R2/R9 proven-safe footprint)

    hipLaunchKernelGGL(k_prep_sent, dim3(Tt / 32, Et / 32, Bt), dim3(256), 0, stream,
                       sent, sentG, sentFB);
    hipLaunchKernelGGL(k_prep_w, dim3(16, 8), dim3(256), 0, stream, W, Wp);
    hipLaunchKernelGGL(k_attnpv, dim3(2048), dim3(256), 0, stream,
                       sentG, sentFB, mask, atr, attnf, Xws);
    hipLaunchKernelGGL(k_out, dim3(Tt / 16, Bt), dim3(256), 0, stream,
                       Xws, Wp, bias, out0);
}

// Round 7
// 232.621 us; speedup vs baseline: 1.1945x; 1.0116x over previous
//
#include <hip/hip_runtime.h>
#include <hip/hip_bf16.h>

// B=16, T=512, E=256, A=8. Inputs f32 (+int32 mask), outputs f32:
//   d_out: [ output 16*512*256 | attn 128*512*512 ]
// R17 == R16 resubmit (round 6 died on infra, no signal). Frag-major Xws:
// k_out needs NO LDS / NO staging / NO barriers -- each A-frag is one
// contiguous 1KB wave load from L2 (XCD-aligned with producer). k_attnpv =
// R12 structure (z=2, 4 attrs, single-attr PV, ~116 VGPR) + bb-major XCD
// swizzle; epilogue writes Xb2 in frag layout (element-traced, re-audited
// R17) and copies 8KB/attr out. R15's fused-GEMM math error documented:
// out row t' = a*64 + t/8, k' = (t%8)*256+e (reshape = memory reinterpret).

#define Bt 16
#define Tt 512
#define Et 256
#define At 8

typedef __attribute__((ext_vector_type(8))) short short8;   // 8 x bf16
typedef __attribute__((ext_vector_type(4))) float floatx4;

static __device__ __forceinline__ unsigned short f2bf(float x) {
    union { float f; unsigned u; } v; v.f = x;
    unsigned r = v.u + 0x7fffu + ((v.u >> 16) & 1u);  // RNE
    return (unsigned short)(r >> 16);
}

static __device__ __forceinline__ floatx4 mfma16(short8 a, short8 b, floatx4 c) {
    return __builtin_amdgcn_mfma_f32_16x16x32_bf16(a, b, c, 0, 0, 0);
}

// Barrier that waits only on LDS ops (lgkmcnt), NOT on in-flight global
// stores (vmcnt). All barriers in k_attnpv protect LDS-only data
// (S / Pb / Xb2 / msk), so lgkm-only is sufficient (audited R11/R12/R16).
static __device__ __forceinline__ void barrier_lds() {
    __builtin_amdgcn_sched_barrier(0);
    asm volatile("s_waitcnt lgkmcnt(0)" ::: "memory");
    __builtin_amdgcn_s_barrier();
    __builtin_amdgcn_sched_barrier(0);
}

// ---- prep: sentG (Gram frags, k=e) + sentFB (PV B-frags, k=s) ------------
__global__ __launch_bounds__(256) void k_prep_sent(const float* __restrict__ sent,
                                                   unsigned short* __restrict__ sentG,
                                                   unsigned short* __restrict__ sentFB) {
    int bb = blockIdx.z;
    int s0 = blockIdx.x * 32;       // 16
    int e0 = blockIdx.y * 32;       // 8
    __shared__ float tile[32][33];
    int c  = threadIdx.x & 31;
    int r4 = threadIdx.x >> 5;
    for (int i = 0; i < 4; ++i) {
        int r = r4 + 8 * i;
        tile[r][c] = sent[(bb * Tt + s0 + r) * Et + e0 + c];
    }
    __syncthreads();
    int wv = threadIdx.x >> 6, lane = threadIdx.x & 63, quad = lane >> 4, l16 = lane & 15;
    union { short8 s; unsigned short e[8]; } u;
    if (wv < 2) {
        // sentG block (bb, st = s0/16 + wv, ec = e0/32)
#pragma unroll
        for (int j = 0; j < 8; ++j) u.e[j] = f2bf(tile[wv * 16 + l16][quad * 8 + j]);
        *(short8*)(sentG + (((size_t)(bb * 32 + (s0 >> 4) + wv)) * 8 + (e0 >> 5)) * 512
                   + lane * 8) = u.s;
    } else {
        int h = wv - 2;
        // sentFB block (bb, et = e0/16 + h, sc = s0/32)
#pragma unroll
        for (int j = 0; j < 8; ++j) u.e[j] = f2bf(tile[quad * 8 + j][h * 16 + l16]);
        *(short8*)(sentFB + (((size_t)(bb * 16 + (e0 >> 4) + h)) * 16 + (s0 >> 5)) * 512
                   + lane * 8) = u.s;
    }
}

// ---- prep: Wp (B-frag-major W), verified R9. Split over 8 y-blocks. ------
__global__ __launch_bounds__(256) void k_prep_w(const float* __restrict__ W,
                                                unsigned short* __restrict__ Wp) {
    int nt = blockIdx.x;                  // 16
    int pc = blockIdx.y;                  // 8 chunks of 2 p-iterations
    int wave = threadIdx.x >> 6, lane = threadIdx.x & 63, quad = lane >> 4, l16 = lane & 15;
    const int KK = At * Et;               // 2048
    for (int p = pc * 2; p < pc * 2 + 2; ++p) {
        int kc = wave + 4 * p;            // 64
        const float* src = W + (size_t)(nt * 16 + l16) * KK + kc * 32 + quad * 8;
        union { short8 s; unsigned short e[8]; } u;
#pragma unroll
        for (int j = 0; j < 8; ++j) u.e[j] = f2bf(src[j]);
        *(short8*)(Wp + (((size_t)nt * 64 + kc) << 9) + lane * 8) = u.s;
    }
}

// ---- fused: Gram + softmax + attn store + PV + frag-major X out ----------
// 1D grid, 1024 blocks. bb-major XCD-chunked swizzle: XCD k owns bb {2k,2k+1}
// (1MB sentG+sentFB working set per XCD L2). Per block: 4 attrs (z*4..+4).
__global__ __launch_bounds__(256) void k_attnpv(const unsigned short* __restrict__ sentG,
                                                const unsigned short* __restrict__ sentFB,
                                                const int* __restrict__ mask,
                                                const float* __restrict__ atr,
                                                float* __restrict__ attnf,
                                                unsigned short* __restrict__ XwsF) {
    int hw = blockIdx.x;                        // 1024, 1024%8==0 -> bijective
    int logical = (hw & 7) * 128 + (hw >> 3);
    int bb = logical >> 6;                      // 16 (slow axis: 2 per XCD)
    int z  = (logical >> 5) & 1;                // a-group 0/1
    int t0 = (logical & 31) * 16;               // 32 tiles
    int a0 = z * 4;
    __shared__ float S[16][516];    // 33 KB; a-loop reuses as Pb(16KB)+Xb2(8KB)
    __shared__ float msk[512];
    __shared__ float mrowv[16];
    unsigned short* Pb  = (unsigned short*)&S[0][0];  // 16 rows x 512 bf16
    unsigned short* Xb2 = Pb + 8192;                  // frag-layout X: 4096 shorts

    int tid = threadIdx.x;
    for (int i = tid; i < 512; i += 256) msk[i] = (mask[bb * Tt + i] != 0) ? 1.0f : 0.0f;
    if (tid < 16) mrowv[tid] = (mask[bb * Tt + t0 + tid] != 0) ? 1.0f : 0.0f;
    barrier_lds();

    int wv = tid >> 6, lane = tid & 63, quad = lane >> 4, l16 = lane & 15;

    // ---- Gram: A and B frags both from frag-major sentG (contiguous 1KB/wave)
    const unsigned short* Gbase = sentG + ((size_t)(bb * 32 + (t0 >> 4)) * 8) * 512 + lane * 8;
    short8 af[8];
#pragma unroll
    for (int kk = 0; kk < 8; ++kk) af[kk] = *(const short8*)(Gbase + kk * 512);

#pragma unroll
    for (int i = 0; i < 8; ++i) {
        int nt = wv * 8 + i;
        const unsigned short* Bb = sentG + ((size_t)(bb * 32 + nt) * 8) * 512 + lane * 8;
        floatx4 c = {0.f, 0.f, 0.f, 0.f};
#pragma unroll
        for (int kk = 0; kk < 8; ++kk)
            c = mfma16(af[kk], *(const short8*)(Bb + kk * 512), c);
#pragma unroll
        for (int r = 0; r < 4; ++r) {
            int cidx = nt * 16 + l16;
            S[quad * 4 + r][cidx] = c[r] * msk[cidx] * mrowv[quad * 4 + r];
        }
    }
    barrier_lds();

    // ---- hoist masked scores to regs; one max-reduction for all attrs
    int row = tid >> 4, cl = tid & 15;
    float w[32];
    float wmax = -1e30f;
#pragma unroll
    for (int i4 = 0; i4 < 8; ++i4) {
        float4 v = *(const float4*)&S[row][i4 * 64 + cl * 4];
        w[i4 * 4 + 0] = v.x; w[i4 * 4 + 1] = v.y; w[i4 * 4 + 2] = v.z; w[i4 * 4 + 3] = v.w;
        wmax = fmaxf(wmax, fmaxf(fmaxf(v.x, v.y), fmaxf(v.z, v.w)));
    }
#pragma unroll
    for (int off = 8; off >= 1; off >>= 1) wmax = fmaxf(wmax, __shfl_xor(wmax, off, 64));
    barrier_lds();    // all S reads done before Pb overwrites the region

    int L = (t0 >> 3) & 15;                 // t'-row base within its 16-tile

    for (int a = a0; a < a0 + 4; ++a) {
        float av = atr[bb * At + a];
        float coef = av * av * (1.0f / 16.0f);
        float mx = coef * wmax;
        float p[32];
        float sum = 0.f;
#pragma unroll
        for (int j = 0; j < 32; ++j) {
            float e = __expf(fmaf(coef, w[j], -mx));
            p[j] = e;
            sum += e;
        }
#pragma unroll
        for (int off = 8; off >= 1; off >>= 1) sum += __shfl_xor(sum, off, 64);
        float inv = 1.0f / sum;
#pragma unroll
        for (int j = 0; j < 32; ++j) p[j] *= inv;

        // attn f32 store (coalesced) -- fire-and-forget; the lgkm-only
        // barriers below do NOT drain these.
        float* orow = attnf + ((size_t)(bb * At + a) * Tt + (t0 + row)) * Tt;
#pragma unroll
        for (int i4 = 0; i4 < 8; ++i4) {
            float4 v;
            v.x = p[i4 * 4 + 0]; v.y = p[i4 * 4 + 1];
            v.z = p[i4 * 4 + 2]; v.w = p[i4 * 4 + 3];
            *(float4*)(orow + i4 * 64 + cl * 4) = v;
        }

        // P -> LDS bf16 in chunk-XOR A-frag layout (cols i4*64+cl*4..+3)
#pragma unroll
        for (int i4 = 0; i4 < 8; ++i4) {
            unsigned b0 = __float_as_uint(p[i4 * 4 + 0]) + 0x8000u;
            unsigned b1 = __float_as_uint(p[i4 * 4 + 1]) + 0x8000u;
            unsigned b2 = __float_as_uint(p[i4 * 4 + 2]) + 0x8000u;
            unsigned b3 = __float_as_uint(p[i4 * 4 + 3]) + 0x8000u;
            uint2 pk;
            pk.x = __builtin_amdgcn_perm(b1, b0, 0x07060302u);
            pk.y = __builtin_amdgcn_perm(b3, b2, 0x07060302u);
            int h = i4 * 8 + (cl >> 1);
            *(uint2*)(Pb + row * 512 + ((h ^ (row & 7)) << 3) + (cl & 1) * 4) = pk;
        }
        barrier_lds();   // Pb writes visible before PV reads (LDS only)

        // PV: 16x256 = P(16x512) @ sf^T; wave wv owns e-tiles wv*4..+3
        floatx4 pacc[4];
#pragma unroll
        for (int i = 0; i < 4; ++i) pacc[i] = (floatx4){0.f, 0.f, 0.f, 0.f};
        for (int kc = 0; kc < 16; ++kc) {
            short8 afr = *(const short8*)(Pb + l16 * 512 +
                (((kc * 4 + quad) ^ (l16 & 7)) << 3));
#pragma unroll
            for (int i = 0; i < 4; ++i) {
                short8 bfr = *(const short8*)(sentFB +
                    (((size_t)(bb * 16 + wv * 4 + i) * 16 + kc) << 9) + lane * 8);
                pacc[i] = mfma16(afr, bfr, pacc[i]);
            }
        }

        // X -> Xb2 in frag layout [kc(64)][quad'(4)][g(2)][j'(8)]:
        //   t' = a*64 + t0/8 + g, k' = (tl&7)*256 + e  (element-traced R16/R17)
#pragma unroll
        for (int i = 0; i < 4; ++i) {
            int W16 = wv * 4 + i;                 // e / 16
            int kcb = W16 >> 1;
            int qp  = (W16 & 1) * 2 + (l16 >> 3);
            int jp  = l16 & 7;
#pragma unroll
            for (int r = 0; r < 4; ++r) {
                int tl = quad * 4 + r;
                Xb2[(((tl & 7) * 8 + kcb) << 6) + qp * 16 + ((tl >> 3) << 3) + jp]
                    = f2bf(av * pacc[i][r]);
            }
        }
        barrier_lds();   // Xb2 visible + all PV Pb-reads drained before copy

        // Xb2 -> XwsF frag blocks (TPT = a*4 + t0/128), rows L, L+1.
        // Fire-and-forget global stores; 8KB per attr.
        {
            int kc = tid >> 2, qp = tid & 3;
            int TPT = (a << 2) + (t0 >> 7);
            size_t base = (((size_t)(bb * 32 + TPT)) * 64 + kc) * 512;
            short8 v0 = *(const short8*)(Xb2 + (kc << 6) + qp * 16);
            short8 v1 = *(const short8*)(Xb2 + (kc << 6) + qp * 16 + 8);
            *(short8*)(XwsF + base + (qp * 16 + L) * 8)     = v0;
            *(short8*)(XwsF + base + (qp * 16 + L + 1) * 8) = v1;
        }
        // next a's Pb writes (disjoint region) follow its own barrier; copy's
        // LDS reads drain at the next lgkmcnt(0) before Xb2 is rewritten.
    }
}

// ---- K3: out = Xr @ W^T + bias. LDS-FREE streaming GEMM ------------------
// 1024 blocks (16 bb x 32 TPT x 2 n-halves), XCD-swizzled bb-major to match
// the producer's L2 placement. A-frags are contiguous 1KB wave loads from
// frag-major XwsF; B-frags from Wp. No LDS, no barriers.
__global__ __launch_bounds__(256) void k_out(const unsigned short* __restrict__ XwsF,
                                             const unsigned short* __restrict__ Wp,
                                             const float* __restrict__ bias,
                                             float* __restrict__ out) {
    int hw = blockIdx.x;                    // 1024, bijective
    int logical = (hw & 7) * 128 + (hw >> 3);
    int bb  = logical >> 6;                 // 16 (2 per XCD)
    int TPT = (logical >> 1) & 31;          // 32
    int nh  = logical & 1;                  // n half
    int tid = threadIdx.x;
    int wv = tid >> 6, lane = tid & 63, quad = lane >> 4, l16 = lane & 15;

    const unsigned short* Abase = XwsF + ((size_t)(bb * 32 + TPT)) * 64 * 512 + lane * 8;
    floatx4 oacc[2];
    oacc[0] = (floatx4){0.f, 0.f, 0.f, 0.f};
    oacc[1] = (floatx4){0.f, 0.f, 0.f, 0.f};
    int nt0 = nh * 8 + wv * 2;
#pragma unroll 4
    for (int kc = 0; kc < 64; ++kc) {
        short8 afr = *(const short8*)(Abase + kc * 512);
#pragma unroll
        for (int i = 0; i < 2; ++i) {
            short8 bf = *(const short8*)(Wp +
                (((size_t)(nt0 + i) * 64 + kc) << 9) + lane * 8);
            oacc[i] = mfma16(afr, bf, oacc[i]);
        }
    }
#pragma unroll
    for (int i = 0; i < 2; ++i) {
        int n = (nt0 + i) * 16 + l16;
        float bv = bias[n];
#pragma unroll
        for (int r = 0; r < 4; ++r) {
            int tp = TPT * 16 + quad * 4 + r;
            out[((size_t)bb * Tt + tp) * Et + n] = oacc[i][r] + bv;
        }
    }
}

extern "C" void kernel_launch(void* const* d_in, const int* in_sizes, int n_in,
                              void* d_out, int out_size, void* d_ws, size_t ws_size,
                              hipStream_t stream) {
    const float* sent = (const float*)d_in[0];   // f32 (B,T,E)
    const int*   mask = (const int*)d_in[1];     // int32 (B,T)
    const float* atr  = (const float*)d_in[2];   // f32 (B,A)
    const float* W    = (const float*)d_in[3];   // f32 (E, A*E)
    const float* bias = (const float*)d_in[4];   // f32 (E)

    float* out0  = (float*)d_out;                     // 2,097,152 f32
    float* attnf = out0 + (size_t)Bt * Tt * Et;       // 33,554,432 f32

    char* ws = (char*)d_ws;
    unsigned short* sentG  = (unsigned short*)(ws);             // 4 MB
    unsigned short* sentFB = (unsigned short*)(ws + 4194304);   // 4 MB
    unsigned short* Wp     = (unsigned short*)(ws + 8388608);   // 1 MB
    unsigned short* XwsF   = (unsigned short*)(ws + 9437184);   // 32 MB frag-major
    // total 42.99 MB (== R2/R9 proven-safe footprint)

    hipLaunchKernelGGL(k_prep_sent, dim3(Tt / 32, Et / 32, Bt), dim3(256), 0, stream,
                       sent, sentG, sentFB);
    hipLaunchKernelGGL(k_prep_w, dim3(16, 8), dim3(256), 0, stream, W, Wp);
    hipLaunchKernelGGL(k_attnpv, dim3(1024), dim3(256), 0, stream,
                       sentG, sentFB, mask, atr, attnf, XwsF);
    hipLaunchKernelGGL(k_out, dim3(1024), dim3(256), 0, stream,
                       XwsF, Wp, bias, out0);
}

// Round 8
// 219.120 us; speedup vs baseline: 1.2681x; 1.0616x over previous
//
#include <hip/hip_runtime.h>
#include <hip/hip_bf16.h>

// B=16, T=512, E=256, A=8. Inputs f32 (+int32 mask), outputs f32:
//   d_out: [ output 16*512*256 | attn 128*512*512 ]
// R18: kc-outer batched PV. R17 budget audit: k_attnpv ~85us is an L2-BW
// term -- PV re-reads sentFB per attr (1MB/block; ~170MB/XCD @ 4.3TB/s ~
// kernel dur). Fix without R13's VGPR blowup: (1) all 4 softmaxes first,
// all 4 Pb in LDS (64KB aliasing dead S; one p[32] live, w[] dies pre-PV);
// (2) ONE batched PV: per kc, 4 bfr loads feed 16 MFMAs (sentFB 4x cut);
// (3) epilogue x4 (R17-verified Xb2/XwsF frag transport + LDS-free k_out).
// LDS 67.6KB -> 2 blocks/CU. Barriers/block 11 -> 6. acc chains keep kc
// order -> bitwise-identical numerics vs R17.

#define Bt 16
#define Tt 512
#define Et 256
#define At 8

typedef __attribute__((ext_vector_type(8))) short short8;   // 8 x bf16
typedef __attribute__((ext_vector_type(4))) float floatx4;

static __device__ __forceinline__ unsigned short f2bf(float x) {
    union { float f; unsigned u; } v; v.f = x;
    unsigned r = v.u + 0x7fffu + ((v.u >> 16) & 1u);  // RNE
    return (unsigned short)(r >> 16);
}

static __device__ __forceinline__ floatx4 mfma16(short8 a, short8 b, floatx4 c) {
    return __builtin_amdgcn_mfma_f32_16x16x32_bf16(a, b, c, 0, 0, 0);
}

// Barrier that waits only on LDS ops (lgkmcnt), NOT on in-flight global
// stores (vmcnt). All barriers in k_attnpv protect LDS-only data
// (S / Pb / Xb2 / msk), so lgkm-only is sufficient (audited R11/R12/R18).
static __device__ __forceinline__ void barrier_lds() {
    __builtin_amdgcn_sched_barrier(0);
    asm volatile("s_waitcnt lgkmcnt(0)" ::: "memory");
    __builtin_amdgcn_s_barrier();
    __builtin_amdgcn_sched_barrier(0);
}

// ---- prep: sentG (Gram frags, k=e) + sentFB (PV B-frags, k=s) ------------
__global__ __launch_bounds__(256) void k_prep_sent(const float* __restrict__ sent,
                                                   unsigned short* __restrict__ sentG,
                                                   unsigned short* __restrict__ sentFB) {
    int bb = blockIdx.z;
    int s0 = blockIdx.x * 32;       // 16
    int e0 = blockIdx.y * 32;       // 8
    __shared__ float tile[32][33];
    int c  = threadIdx.x & 31;
    int r4 = threadIdx.x >> 5;
    for (int i = 0; i < 4; ++i) {
        int r = r4 + 8 * i;
        tile[r][c] = sent[(bb * Tt + s0 + r) * Et + e0 + c];
    }
    __syncthreads();
    int wv = threadIdx.x >> 6, lane = threadIdx.x & 63, quad = lane >> 4, l16 = lane & 15;
    union { short8 s; unsigned short e[8]; } u;
    if (wv < 2) {
        // sentG block (bb, st = s0/16 + wv, ec = e0/32)
#pragma unroll
        for (int j = 0; j < 8; ++j) u.e[j] = f2bf(tile[wv * 16 + l16][quad * 8 + j]);
        *(short8*)(sentG + (((size_t)(bb * 32 + (s0 >> 4) + wv)) * 8 + (e0 >> 5)) * 512
                   + lane * 8) = u.s;
    } else {
        int h = wv - 2;
        // sentFB block (bb, et = e0/16 + h, sc = s0/32)
#pragma unroll
        for (int j = 0; j < 8; ++j) u.e[j] = f2bf(tile[quad * 8 + j][h * 16 + l16]);
        *(short8*)(sentFB + (((size_t)(bb * 16 + (e0 >> 4) + h)) * 16 + (s0 >> 5)) * 512
                   + lane * 8) = u.s;
    }
}

// ---- prep: Wp (B-frag-major W), verified R9. Split over 8 y-blocks. ------
__global__ __launch_bounds__(256) void k_prep_w(const float* __restrict__ W,
                                                unsigned short* __restrict__ Wp) {
    int nt = blockIdx.x;                  // 16
    int pc = blockIdx.y;                  // 8 chunks of 2 p-iterations
    int wave = threadIdx.x >> 6, lane = threadIdx.x & 63, quad = lane >> 4, l16 = lane & 15;
    const int KK = At * Et;               // 2048
    for (int p = pc * 2; p < pc * 2 + 2; ++p) {
        int kc = wave + 4 * p;            // 64
        const float* src = W + (size_t)(nt * 16 + l16) * KK + kc * 32 + quad * 8;
        union { short8 s; unsigned short e[8]; } u;
#pragma unroll
        for (int j = 0; j < 8; ++j) u.e[j] = f2bf(src[j]);
        *(short8*)(Wp + (((size_t)nt * 64 + kc) << 9) + lane * 8) = u.s;
    }
}

// ---- fused: Gram + 4x softmax + batched PV + frag-major X out ------------
// 1D grid, 1024 blocks. bb-major XCD-chunked swizzle: XCD k owns bb {2k,2k+1}
// (1MB sentG+sentFB working set per XCD L2). Per block: 4 attrs (z*4..+4).
__global__ __launch_bounds__(256) void k_attnpv(const unsigned short* __restrict__ sentG,
                                                const unsigned short* __restrict__ sentFB,
                                                const int* __restrict__ mask,
                                                const float* __restrict__ atr,
                                                float* __restrict__ attnf,
                                                unsigned short* __restrict__ XwsF) {
    int hw = blockIdx.x;                        // 1024, 1024%8==0 -> bijective
    int logical = (hw & 7) * 128 + (hw >> 3);
    int bb = logical >> 6;                      // 16 (slow axis: 2 per XCD)
    int z  = (logical >> 5) & 1;                // a-group 0/1
    int t0 = (logical & 31) * 16;               // 32 tiles
    int a0 = z * 4;

    // 64 KB region: phase A = S[16][516] scores; phase B = Pb[4][8192] bf16;
    // phase C = Xb2[4][4096] bf16 (aliases Pb[0..1] after barrier).
    __shared__ __align__(16) float Sbuf[16384];
    __shared__ float msk[512];
    __shared__ float mrowv[16];
    unsigned short* Pb  = (unsigned short*)Sbuf;
    unsigned short* Xb2 = (unsigned short*)Sbuf;

    int tid = threadIdx.x;
    for (int i = tid; i < 512; i += 256) msk[i] = (mask[bb * Tt + i] != 0) ? 1.0f : 0.0f;
    if (tid < 16) mrowv[tid] = (mask[bb * Tt + t0 + tid] != 0) ? 1.0f : 0.0f;
    barrier_lds();

    int wv = tid >> 6, lane = tid & 63, quad = lane >> 4, l16 = lane & 15;

    // ---- Gram: A and B frags both from frag-major sentG (contiguous 1KB/wave)
    const unsigned short* Gbase = sentG + ((size_t)(bb * 32 + (t0 >> 4)) * 8) * 512 + lane * 8;
    short8 af[8];
#pragma unroll
    for (int kk = 0; kk < 8; ++kk) af[kk] = *(const short8*)(Gbase + kk * 512);

#pragma unroll
    for (int i = 0; i < 8; ++i) {
        int nt = wv * 8 + i;
        const unsigned short* Bb = sentG + ((size_t)(bb * 32 + nt) * 8) * 512 + lane * 8;
        floatx4 c = {0.f, 0.f, 0.f, 0.f};
#pragma unroll
        for (int kk = 0; kk < 8; ++kk)
            c = mfma16(af[kk], *(const short8*)(Bb + kk * 512), c);
#pragma unroll
        for (int r = 0; r < 4; ++r) {
            int cidx = nt * 16 + l16;
            Sbuf[(quad * 4 + r) * 516 + cidx] = c[r] * msk[cidx] * mrowv[quad * 4 + r];
        }
    }
    barrier_lds();

    // ---- hoist masked scores to regs; one max-reduction for all attrs
    int row = tid >> 4, cl = tid & 15;
    float w[32];
    float wmax = -1e30f;
#pragma unroll
    for (int i4 = 0; i4 < 8; ++i4) {
        float4 v = *(const float4*)&Sbuf[row * 516 + i4 * 64 + cl * 4];
        w[i4 * 4 + 0] = v.x; w[i4 * 4 + 1] = v.y; w[i4 * 4 + 2] = v.z; w[i4 * 4 + 3] = v.w;
        wmax = fmaxf(wmax, fmaxf(fmaxf(v.x, v.y), fmaxf(v.z, v.w)));
    }
#pragma unroll
    for (int off = 8; off >= 1; off >>= 1) wmax = fmaxf(wmax, __shfl_xor(wmax, off, 64));
    barrier_lds();    // all S reads done before Pb overwrites the region

    int L = (t0 >> 3) & 15;                 // t'-row base within its 16-tile

    // ---- phase 1: all 4 softmaxes -> attn stores + Pb[al] (one p[] live)
#pragma unroll
    for (int al = 0; al < 4; ++al) {
        int a = a0 + al;
        float av = atr[bb * At + a];
        float coef = av * av * (1.0f / 16.0f);
        float mx = coef * wmax;
        float p[32];
        float sum = 0.f;
#pragma unroll
        for (int j = 0; j < 32; ++j) {
            float e = __expf(fmaf(coef, w[j], -mx));
            p[j] = e;
            sum += e;
        }
#pragma unroll
        for (int off = 8; off >= 1; off >>= 1) sum += __shfl_xor(sum, off, 64);
        float inv = 1.0f / sum;
#pragma unroll
        for (int j = 0; j < 32; ++j) p[j] *= inv;

        // attn f32 store (coalesced) -- fire-and-forget; the lgkm-only
        // barriers below do NOT drain these.
        float* orow = attnf + ((size_t)(bb * At + a) * Tt + (t0 + row)) * Tt;
#pragma unroll
        for (int i4 = 0; i4 < 8; ++i4) {
            float4 v;
            v.x = p[i4 * 4 + 0]; v.y = p[i4 * 4 + 1];
            v.z = p[i4 * 4 + 2]; v.w = p[i4 * 4 + 3];
            *(float4*)(orow + i4 * 64 + cl * 4) = v;
        }

        // P -> Pb[al] bf16 in chunk-XOR A-frag layout
#pragma unroll
        for (int i4 = 0; i4 < 8; ++i4) {
            unsigned b0 = __float_as_uint(p[i4 * 4 + 0]) + 0x8000u;
            unsigned b1 = __float_as_uint(p[i4 * 4 + 1]) + 0x8000u;
            unsigned b2 = __float_as_uint(p[i4 * 4 + 2]) + 0x8000u;
            unsigned b3 = __float_as_uint(p[i4 * 4 + 3]) + 0x8000u;
            uint2 pk;
            pk.x = __builtin_amdgcn_perm(b1, b0, 0x07060302u);
            pk.y = __builtin_amdgcn_perm(b3, b2, 0x07060302u);
            int h = i4 * 8 + (cl >> 1);
            *(uint2*)(Pb + al * 8192 + row * 512 + ((h ^ (row & 7)) << 3)
                      + (cl & 1) * 4) = pk;
        }
    }
    barrier_lds();   // all Pb visible before PV reads (LDS only)

    // ---- phase 2: batched PV -- each bfr load feeds 4 attrs (16 MFMAs/kc)
    floatx4 acc[4][4];
#pragma unroll
    for (int al = 0; al < 4; ++al)
#pragma unroll
        for (int i = 0; i < 4; ++i) acc[al][i] = (floatx4){0.f, 0.f, 0.f, 0.f};

    for (int kc = 0; kc < 16; ++kc) {
        short8 bfr[4];
#pragma unroll
        for (int i = 0; i < 4; ++i)
            bfr[i] = *(const short8*)(sentFB +
                (((size_t)(bb * 16 + wv * 4 + i) * 16 + kc) << 9) + lane * 8);
#pragma unroll
        for (int al = 0; al < 4; ++al) {
            short8 afr = *(const short8*)(Pb + al * 8192 + l16 * 512 +
                (((kc * 4 + quad) ^ (l16 & 7)) << 3));
#pragma unroll
            for (int i = 0; i < 4; ++i)
                acc[al][i] = mfma16(afr, bfr[i], acc[al][i]);
        }
    }
    barrier_lds();   // all PV Pb-reads drained before Xb2 overwrites region

    // ---- phase 3: epilogue x4 -- Xb2[al] frag layout (R17-verified):
    //   t' = a*64 + t0/8 + g, k' = (tl&7)*256 + e
#pragma unroll
    for (int al = 0; al < 4; ++al) {
        float av = atr[bb * At + a0 + al];
#pragma unroll
        for (int i = 0; i < 4; ++i) {
            int W16 = wv * 4 + i;                 // e / 16
            int kcb = W16 >> 1;
            int qp  = (W16 & 1) * 2 + (l16 >> 3);
            int jp  = l16 & 7;
#pragma unroll
            for (int r = 0; r < 4; ++r) {
                int tl = quad * 4 + r;
                Xb2[al * 4096 + (((tl & 7) * 8 + kcb) << 6) + qp * 16
                    + ((tl >> 3) << 3) + jp] = f2bf(av * acc[al][i][r]);
            }
        }
    }
    barrier_lds();   // Xb2 visible before copy reads (LDS only)

    // ---- Xb2 -> XwsF frag blocks (TPT = a*4 + t0/128), rows L, L+1.
#pragma unroll
    for (int al = 0; al < 4; ++al) {
        int a = a0 + al;
        int kc = tid >> 2, qp = tid & 3;
        int TPT = (a << 2) + (t0 >> 7);
        size_t base = (((size_t)(bb * 32 + TPT)) * 64 + kc) * 512;
        short8 v0 = *(const short8*)(Xb2 + al * 4096 + (kc << 6) + qp * 16);
        short8 v1 = *(const short8*)(Xb2 + al * 4096 + (kc << 6) + qp * 16 + 8);
        *(short8*)(XwsF + base + (qp * 16 + L) * 8)     = v0;
        *(short8*)(XwsF + base + (qp * 16 + L + 1) * 8) = v1;
    }
}

// ---- K3: out = Xr @ W^T + bias. LDS-FREE streaming GEMM (R17-verified) ---
// 1024 blocks (16 bb x 32 TPT x 2 n-halves), XCD-swizzled bb-major to match
// the producer's L2 placement. A-frags are contiguous 1KB wave loads from
// frag-major XwsF; B-frags from Wp. No LDS, no barriers.
__global__ __launch_bounds__(256) void k_out(const unsigned short* __restrict__ XwsF,
                                             const unsigned short* __restrict__ Wp,
                                             const float* __restrict__ bias,
                                             float* __restrict__ out) {
    int hw = blockIdx.x;                    // 1024, bijective
    int logical = (hw & 7) * 128 + (hw >> 3);
    int bb  = logical >> 6;                 // 16 (2 per XCD)
    int TPT = (logical >> 1) & 31;          // 32
    int nh  = logical & 1;                  // n half
    int tid = threadIdx.x;
    int wv = tid >> 6, lane = tid & 63, quad = lane >> 4, l16 = lane & 15;

    const unsigned short* Abase = XwsF + ((size_t)(bb * 32 + TPT)) * 64 * 512 + lane * 8;
    floatx4 oacc[2];
    oacc[0] = (floatx4){0.f, 0.f, 0.f, 0.f};
    oacc[1] = (floatx4){0.f, 0.f, 0.f, 0.f};
    int nt0 = nh * 8 + wv * 2;
#pragma unroll 4
    for (int kc = 0; kc < 64; ++kc) {
        short8 afr = *(const short8*)(Abase + kc * 512);
#pragma unroll
        for (int i = 0; i < 2; ++i) {
            short8 bf = *(const short8*)(Wp +
                (((size_t)(nt0 + i) * 64 + kc) << 9) + lane * 8);
            oacc[i] = mfma16(afr, bf, oacc[i]);
        }
    }
#pragma unroll
    for (int i = 0; i < 2; ++i) {
        int n = (nt0 + i) * 16 + l16;
        float bv = bias[n];
#pragma unroll
        for (int r = 0; r < 4; ++r) {
            int tp = TPT * 16 + quad * 4 + r;
            out[((size_t)bb * Tt + tp) * Et + n] = oacc[i][r] + bv;
        }
    }
}

extern "C" void kernel_launch(void* const* d_in, const int* in_sizes, int n_in,
                              void* d_out, int out_size, void* d_ws, size_t ws_size,
                              hipStream_t stream) {
    const float* sent = (const float*)d_in[0];   // f32 (B,T,E)
    const int*   mask = (const int*)d_in[1];     // int32 (B,T)
    const float* atr  = (const float*)d_in[2];   // f32 (B,A)
    const float* W    = (const float*)d_in[3];   // f32 (E, A*E)
    const float* bias = (const float*)d_in[4];   // f32 (E)

    float* out0  = (float*)d_out;                     // 2,097,152 f32
    float* attnf = out0 + (size_t)Bt * Tt * Et;       // 33,554,432 f32

    char* ws = (char*)d_ws;
    unsigned short* sentG  = (unsigned short*)(ws);             // 4 MB
    unsigned short* sentFB = (unsigned short*)(ws + 4194304);   // 4 MB
    unsigned short* Wp     = (unsigned short*)(ws + 8388608);   // 1 MB
    unsigned short* XwsF   = (unsigned short*)(ws + 9437184);   // 32 MB frag-major
    // total 42.99 MB (== R2/R9 proven-safe footprint)

    hipLaunchKernelGGL(k_prep_sent, dim3(Tt / 32, Et / 32, Bt), dim3(256), 0, stream,
                       sent, sentG, sentFB);
    hipLaunchKernelGGL(k_prep_w, dim3(16, 8), dim3(256), 0, stream, W, Wp);
    hipLaunchKernelGGL(k_attnpv, dim3(1024), dim3(256), 0, stream,
                       sentG, sentFB, mask, atr, attnf, XwsF);
    hipLaunchKernelGGL(k_out, dim3(1024), dim3(256), 0, stream,
                       XwsF, Wp, bias, out0);
}